// Round 6
// baseline (795.214 us; speedup 1.0000x reference)
//
#include <hip/hip_runtime.h>
#include <hip/hip_bf16.h>
#include <stdint.h>

#define TS 524288u
#define TMASK (TS - 1u)

typedef __attribute__((ext_vector_type(8))) short bf16x8;
typedef __attribute__((ext_vector_type(4))) short short4v;
typedef __attribute__((ext_vector_type(4))) float f32x4;

__device__ __forceinline__ short f2bf(float f) {
    union { float f; uint32_t u; } v; v.f = f;
    const uint32_t r = (v.u + 0x7fffu + ((v.u >> 16) & 1u)) >> 16;  // RNE
    return (short)r;
}
__device__ __forceinline__ float bflo(uint32_t u) { return __uint_as_float(u << 16); }
__device__ __forceinline__ float bfhi(uint32_t u) { return __uint_as_float(u & 0xffff0000u); }

__constant__ float c_NLf[16] = {16.f,22.f,30.f,42.f,58.f,80.f,111.f,153.f,
                                212.f,293.f,406.f,561.f,775.f,1071.f,1481.f,2046.f};

// K0: f32 tables -> packed bf16 dwords (33 MB; nearly fits aggregate L2).
__global__ __launch_bounds__(256)
void cvt_tables(const float2* __restrict__ src, uint32_t* __restrict__ dst, int npairs)
{
    const int i = blockIdx.x * 256 + threadIdx.x;
    if (i >= npairs) return;
    const float2 v = src[i];
    dst[i] = (uint32_t)(uint16_t)f2bf(v.x) | ((uint32_t)(uint16_t)f2bf(v.y) << 16);
}

// ---------------------------------------------------------------------------
// Fused encode + MFMA MLP. Persistent blocks, 4 waves/block, wave = 16 points.
// Encode->MFMA register handoff: B-frag element k=quad*8+e is (level
// 4*quad+(e>>1), feature e&1), so lane (p16,quad) computes the hash encode
// for its own 4 levels and the result IS the MFMA B operand — no feats
// memory, 32 independent gathers in flight per lane.
// No inter-layer __syncthreads: act buffers are per-wave, so gather-stalled
// waves co-schedule with MFMA-phase waves (m114 overlap).
// ---------------------------------------------------------------------------
#define ACT_STRIDE 72

template<bool PACKED>
__global__ __launch_bounds__(256)
void ngp_fused(const float* __restrict__ xg, const float* __restrict__ dg,
               const void* __restrict__ tables,
               const float* __restrict__ dW1, const float* __restrict__ db1,
               const float* __restrict__ dW2, const float* __restrict__ db2,
               const float* __restrict__ cW1, const float* __restrict__ cb1,
               const float* __restrict__ cW2, const float* __restrict__ cb2,
               const float* __restrict__ cW3, const float* __restrict__ cb3,
               float* __restrict__ out, int n)
{
    __shared__ __align__(16) short w1[2048];   // [jb4][lane64][e8]       L1: 32->64
    __shared__ __align__(16) short w2[1024];   // [kb2][lane64][e8]       L2: 64->16
    __shared__ __align__(16) short w3[4096];   // [jb4][kb2][lane64][e8]  L3: 64(pad43)->64
    __shared__ __align__(16) short w4[4096];   // [jb4][kb2][lane64][e8]  L4: 64->64
    __shared__ __align__(16) short w5[1024];   // [kb2][lane64][e8]       L5: 64->16(3 used)
    __shared__ float b1[64], b2[16], b3[64], b4[64], b5[16];
    __shared__ __align__(16) short act[4][2][16*ACT_STRIDE];   // [wave][buf][p*stride+k]

    const int tid = threadIdx.x;

    // ---- prepack weights (once per persistent block) ----
    for (int idx = tid; idx < 2048; idx += 256) {
        const int jb = idx >> 9, lane = (idx >> 3) & 63, e = idx & 7;
        const int j = jb*16 + (lane & 15), k = ((lane >> 4) << 3) + e;
        w1[idx] = f2bf(dW1[k*64 + j]);
    }
    for (int idx = tid; idx < 1024; idx += 256) {
        const int kb = idx >> 9, lane = (idx >> 3) & 63, e = idx & 7;
        const int j = lane & 15, k = kb*32 + ((lane >> 4) << 3) + e;
        w2[idx] = f2bf(dW2[k*16 + j]);
    }
    for (int idx = tid; idx < 4096; idx += 256) {
        const int jb = idx >> 10, kb = (idx >> 9) & 1, lane = (idx >> 3) & 63, e = idx & 7;
        const int j = jb*16 + (lane & 15), k = kb*32 + ((lane >> 4) << 3) + e;
        w3[idx] = (k < 43) ? f2bf(cW1[k*64 + j]) : (short)0;
        w4[idx] = f2bf(cW2[k*64 + j]);
    }
    for (int idx = tid; idx < 1024; idx += 256) {
        const int kb = idx >> 9, lane = (idx >> 3) & 63, e = idx & 7;
        const int j = lane & 15, k = kb*32 + ((lane >> 4) << 3) + e;
        w5[idx] = (j < 3) ? f2bf(cW3[k*3 + j]) : (short)0;
    }
    if (tid < 64) { b1[tid] = db1[tid]; b3[tid] = cb1[tid]; b4[tid] = cb2[tid]; }
    if (tid < 16) { b2[tid] = db2[tid]; b5[tid] = (tid < 3) ? cb3[tid] : 0.0f; }
    __syncthreads();   // the ONLY barrier: weights read-only afterwards

    const int wv = tid >> 6, lane = tid & 63;
    const int p16 = lane & 15, quad = lane >> 4;
    short* buf0 = &act[wv][0][0];
    short* buf1 = &act[wv][1][0];

    // this lane's 4 level scales (levels 4*quad .. 4*quad+3), hoisted
    const float nf0 = c_NLf[4*quad+0], nf1 = c_NLf[4*quad+1];
    const float nf2 = c_NLf[4*quad+2], nf3 = c_NLf[4*quad+3];

    const int ntiles = (n + 63) >> 6;
    for (int t = blockIdx.x; t < ntiles; t += gridDim.x) {
        const int pp_raw = t*64 + wv*16 + p16;
        const int pp = (pp_raw < n) ? pp_raw : (n - 1);
        const bool valid = (pp_raw < n);

        const float px = xg[3*pp+0], py = xg[3*pp+1], pz = xg[3*pp+2];
        float sx = px / 3.0f, sy = py / 3.0f, sz = pz / 3.0f;
        const bool inside = (fabsf(sx) < 0.5f) && (fabsf(sy) < 0.5f) && (fabsf(sz) < 0.5f);
        sx = fminf(fmaxf(sx + 0.5f, 0.0f), 1.0f);
        sy = fminf(fmaxf(sy + 0.5f, 0.0f), 1.0f);
        sz = fminf(fmaxf(sz + 0.5f, 0.0f), 1.0f);

        // ---- encode this lane's 4 levels straight into the B-frag ----
        bf16x8 bA;
        const float nfv[4] = {nf0, nf1, nf2, nf3};
        #pragma unroll
        for (int li = 0; li < 4; ++li) {
            const float nf = nfv[li];
            const int l = 4*quad + li;
            const float xn0 = sx * nf, xn1 = sy * nf, xn2 = sz * nf;
            const float fl0 = floorf(xn0), fl1 = floorf(xn1), fl2 = floorf(xn2);
            const float w0 = xn0 - fl0, w1v = xn1 - fl1, w2v = xn2 - fl2;
            const uint32_t f0 = (uint32_t)fl0, f1 = (uint32_t)fl1, f2 = (uint32_t)fl2;
            const uint32_t c0 = (uint32_t)ceilf(xn0);
            const uint32_t c1 = (uint32_t)ceilf(xn1);
            const uint32_t c2 = (uint32_t)ceilf(xn2);
            const uint32_t hyf = f1 * 2654435761u, hyc = c1 * 2654435761u;
            const uint32_t hzf = f2 * 805459861u,  hzc = c2 * 805459861u;
            const uint32_t h0 = (f0 ^ hyf ^ hzf) & TMASK, h1 = (c0 ^ hyf ^ hzf) & TMASK;
            const uint32_t h2 = (f0 ^ hyc ^ hzf) & TMASK, h3 = (c0 ^ hyc ^ hzf) & TMASK;
            const uint32_t h4 = (f0 ^ hyf ^ hzc) & TMASK, h5 = (c0 ^ hyf ^ hzc) & TMASK;
            const uint32_t h6 = (f0 ^ hyc ^ hzc) & TMASK, h7 = (c0 ^ hyc ^ hzc) & TMASK;

            float v0x,v0y,v1x,v1y,v2x,v2y,v3x,v3y,v4x,v4y,v5x,v5y,v6x,v6y,v7x,v7y;
            if (PACKED) {
                const uint32_t* tb = (const uint32_t*)tables + (size_t)l * TS;
                const uint32_t e0 = tb[h0], e1 = tb[h1], e2 = tb[h2], e3 = tb[h3];
                const uint32_t e4 = tb[h4], e5 = tb[h5], e6 = tb[h6], e7 = tb[h7];
                v0x = bflo(e0); v0y = bfhi(e0); v1x = bflo(e1); v1y = bfhi(e1);
                v2x = bflo(e2); v2y = bfhi(e2); v3x = bflo(e3); v3y = bfhi(e3);
                v4x = bflo(e4); v4y = bfhi(e4); v5x = bflo(e5); v5y = bfhi(e5);
                v6x = bflo(e6); v6y = bfhi(e6); v7x = bflo(e7); v7y = bfhi(e7);
            } else {
                const float2* tb = (const float2*)tables + (size_t)l * TS;
                const float2 e0 = tb[h0], e1 = tb[h1], e2 = tb[h2], e3 = tb[h3];
                const float2 e4 = tb[h4], e5 = tb[h5], e6 = tb[h6], e7 = tb[h7];
                v0x = e0.x; v0y = e0.y; v1x = e1.x; v1y = e1.y;
                v2x = e2.x; v2y = e2.y; v3x = e3.x; v3y = e3.y;
                v4x = e4.x; v4y = e4.y; v5x = e5.x; v5y = e5.y;
                v6x = e6.x; v6y = e6.y; v7x = e7.x; v7y = e7.y;
            }

            const float u0 = 1.0f - w0, u1 = 1.0f - w1v, u2 = 1.0f - w2v;
            float a0, a1;
            a0 = u0*u1*u2 * v0x;               a1 = u0*u1*u2 * v0y;
            a0 = fmaf(w0*u1*u2,  v1x, a0);     a1 = fmaf(w0*u1*u2,  v1y, a1);
            a0 = fmaf(u0*w1v*u2, v2x, a0);     a1 = fmaf(u0*w1v*u2, v2y, a1);
            a0 = fmaf(w0*w1v*u2, v3x, a0);     a1 = fmaf(w0*w1v*u2, v3y, a1);
            a0 = fmaf(u0*u1*w2v, v4x, a0);     a1 = fmaf(u0*u1*w2v, v4y, a1);
            a0 = fmaf(w0*u1*w2v, v5x, a0);     a1 = fmaf(w0*u1*w2v, v5y, a1);
            a0 = fmaf(u0*w1v*w2v,v6x, a0);     a1 = fmaf(u0*w1v*w2v,v6y, a1);
            a0 = fmaf(w0*w1v*w2v,v7x, a0);     a1 = fmaf(w0*w1v*w2v,v7y, a1);

            bA[2*li+0] = f2bf(a0);
            bA[2*li+1] = f2bf(a1);
        }

        // ---- L1: feats[32] -> hid[64], relu ----
        #pragma unroll
        for (int jb = 0; jb < 4; ++jb) {
            const int j0 = jb*16 + quad*4;
            f32x4 acc = { b1[j0], b1[j0+1], b1[j0+2], b1[j0+3] };
            const bf16x8 aF = *reinterpret_cast<const bf16x8*>(&w1[(jb*64 + lane)*8]);
            acc = __builtin_amdgcn_mfma_f32_16x16x32_bf16(aF, bA, acc, 0, 0, 0);
            short4v s;
            s[0] = f2bf(fmaxf(acc[0], 0.f)); s[1] = f2bf(fmaxf(acc[1], 0.f));
            s[2] = f2bf(fmaxf(acc[2], 0.f)); s[3] = f2bf(fmaxf(acc[3], 0.f));
            *reinterpret_cast<short4v*>(&buf0[p16*ACT_STRIDE + j0]) = s;
        }

        // ---- L2: hid[64] -> h16[16] (no relu) ----
        f32x4 acc2 = { b2[quad*4], b2[quad*4+1], b2[quad*4+2], b2[quad*4+3] };
        #pragma unroll
        for (int kb = 0; kb < 2; ++kb) {
            const bf16x8 bF = *reinterpret_cast<const bf16x8*>(&buf0[p16*ACT_STRIDE + kb*32 + quad*8]);
            const bf16x8 aF = *reinterpret_cast<const bf16x8*>(&w2[(kb*64 + lane)*8]);
            acc2 = __builtin_amdgcn_mfma_f32_16x16x32_bf16(aF, bF, acc2, 0, 0, 0);
        }
        if (quad == 0 && valid)
            out[(size_t)3*n + pp] = inside ? __expf(acc2[0]) : 0.0f;
        {
            short4v s;
            s[0] = f2bf(acc2[0]); s[1] = f2bf(acc2[1]);
            s[2] = f2bf(acc2[2]); s[3] = f2bf(acc2[3]);
            *reinterpret_cast<short4v*>(&buf1[p16*ACT_STRIDE + quad*4]) = s;
        }
        {   // pos-enc -> buf1[p][16..42], zeros [43..63]
            const float d0 = dg[3*pp+0], d1 = dg[3*pp+1], d2 = dg[3*pp+2];
            for (int idx = 16 + quad; idx < 64; idx += 4) {
                float val = 0.0f;
                if (idx < 19) {
                    val = (idx == 16) ? d0 : ((idx == 17) ? d1 : d2);
                } else if (idx < 43) {
                    const int g = idx - 19, f = g / 6, rem = g - 6*f;
                    const int c = (rem < 3) ? rem : rem - 3;
                    const float arg = ((c == 0) ? d0 : ((c == 1) ? d1 : d2)) * (float)(1 << f);
                    val = (rem < 3) ? __sinf(arg) : __cosf(arg);
                }
                buf1[p16*ACT_STRIDE + idx] = f2bf(val);
            }
        }

        // ---- L3: cin[64(pad)] -> c1[64], relu ----
        #pragma unroll
        for (int jb = 0; jb < 4; ++jb) {
            const int j0 = jb*16 + quad*4;
            f32x4 acc = { b3[j0], b3[j0+1], b3[j0+2], b3[j0+3] };
            #pragma unroll
            for (int kb = 0; kb < 2; ++kb) {
                const bf16x8 bF = *reinterpret_cast<const bf16x8*>(&buf1[p16*ACT_STRIDE + kb*32 + quad*8]);
                const bf16x8 aF = *reinterpret_cast<const bf16x8*>(&w3[((jb*2 + kb)*64 + lane)*8]);
                acc = __builtin_amdgcn_mfma_f32_16x16x32_bf16(aF, bF, acc, 0, 0, 0);
            }
            short4v s;
            s[0] = f2bf(fmaxf(acc[0], 0.f)); s[1] = f2bf(fmaxf(acc[1], 0.f));
            s[2] = f2bf(fmaxf(acc[2], 0.f)); s[3] = f2bf(fmaxf(acc[3], 0.f));
            *reinterpret_cast<short4v*>(&buf0[p16*ACT_STRIDE + j0]) = s;
        }

        // ---- L4: c1[64] -> c2[64], relu ----
        #pragma unroll
        for (int jb = 0; jb < 4; ++jb) {
            const int j0 = jb*16 + quad*4;
            f32x4 acc = { b4[j0], b4[j0+1], b4[j0+2], b4[j0+3] };
            #pragma unroll
            for (int kb = 0; kb < 2; ++kb) {
                const bf16x8 bF = *reinterpret_cast<const bf16x8*>(&buf0[p16*ACT_STRIDE + kb*32 + quad*8]);
                const bf16x8 aF = *reinterpret_cast<const bf16x8*>(&w4[((jb*2 + kb)*64 + lane)*8]);
                acc = __builtin_amdgcn_mfma_f32_16x16x32_bf16(aF, bF, acc, 0, 0, 0);
            }
            short4v s;
            s[0] = f2bf(fmaxf(acc[0], 0.f)); s[1] = f2bf(fmaxf(acc[1], 0.f));
            s[2] = f2bf(fmaxf(acc[2], 0.f)); s[3] = f2bf(fmaxf(acc[3], 0.f));
            *reinterpret_cast<short4v*>(&buf1[p16*ACT_STRIDE + j0]) = s;
        }

        // ---- L5: c2[64] -> 16 (3 used), sigmoid, masked store ----
        f32x4 acc5 = { b5[quad*4], b5[quad*4+1], b5[quad*4+2], b5[quad*4+3] };
        #pragma unroll
        for (int kb = 0; kb < 2; ++kb) {
            const bf16x8 bF = *reinterpret_cast<const bf16x8*>(&buf1[p16*ACT_STRIDE + kb*32 + quad*8]);
            const bf16x8 aF = *reinterpret_cast<const bf16x8*>(&w5[(kb*64 + lane)*8]);
            acc5 = __builtin_amdgcn_mfma_f32_16x16x32_bf16(aF, bF, acc5, 0, 0, 0);
        }
        if (quad == 0 && valid) {
            #pragma unroll
            for (int r = 0; r < 3; ++r) {
                const float s = 1.0f / (1.0f + __expf(-acc5[r]));
                out[3*pp + r] = inside ? s : 0.0f;
            }
        }
        // no __syncthreads: act buffers are per-wave; same-wave LDS deps are
        // handled by compiler-inserted lgkmcnt waits
    }
}

extern "C" void kernel_launch(void* const* d_in, const int* in_sizes, int n_in,
                              void* d_out, int out_size, void* d_ws, size_t ws_size,
                              hipStream_t stream)
{
    const float* x   = (const float*)d_in[0];
    const float* d   = (const float*)d_in[1];
    const float* tb  = (const float*)d_in[2];
    const float* dW1 = (const float*)d_in[3];
    const float* db1 = (const float*)d_in[4];
    const float* dW2 = (const float*)d_in[5];
    const float* db2 = (const float*)d_in[6];
    const float* cW1 = (const float*)d_in[7];
    const float* cb1 = (const float*)d_in[8];
    const float* cW2 = (const float*)d_in[9];
    const float* cb2 = (const float*)d_in[10];
    const float* cW3 = (const float*)d_in[11];
    const float* cb3 = (const float*)d_in[12];
    float* out = (float*)d_out;

    const int n = in_sizes[0] / 3;                   // N_PTS = 1M
    const size_t tb16_bytes = (size_t)16 * TS * 4;   // 32 MB packed bf16 tables
    uint32_t* tb16 = (uint32_t*)d_ws;
    const bool packed_ok = (ws_size >= tb16_bytes);

    if (packed_ok) {
        const int npairs = 16 * (int)TS;
        dim3 block(256), grid((npairs + 255) / 256);
        hipLaunchKernelGGL(cvt_tables, grid, block, 0, stream,
                           (const float2*)tb, tb16, npairs);
    }

    const int ntiles = (n + 63) >> 6;
    const int nblk = (ntiles < 768) ? ntiles : 768;  // persistent blocks, ~3/CU (LDS-limited)
    dim3 block(256), grid(nblk);
    if (packed_ok)
        hipLaunchKernelGGL((ngp_fused<true>),  grid, block, 0, stream,
                           x, d, (const void*)tb16, dW1, db1, dW2, db2,
                           cW1, cb1, cW2, cb2, cW3, cb3, out, n);
    else
        hipLaunchKernelGGL((ngp_fused<false>), grid, block, 0, stream,
                           x, d, (const void*)tb,   dW1, db1, dW2, db2,
                           cW1, cb1, cW2, cb2, cW3, cb3, out, n);
}

// Round 7
// 598.817 us; speedup vs baseline: 1.3280x; 1.3280x over previous
//
#include <hip/hip_runtime.h>
#include <hip/hip_bf16.h>
#include <stdint.h>

#define TS 524288u
#define TMASK (TS - 1u)

typedef __attribute__((ext_vector_type(8))) short bf16x8;
typedef __attribute__((ext_vector_type(4))) short short4v;
typedef __attribute__((ext_vector_type(4))) float f32x4;

__device__ __forceinline__ short f2bf(float f) {
    union { float f; uint32_t u; } v; v.f = f;
    const uint32_t r = (v.u + 0x7fffu + ((v.u >> 16) & 1u)) >> 16;  // RNE
    return (short)r;
}
__device__ __forceinline__ float bflo(uint32_t u) { return __uint_as_float(u << 16); }
__device__ __forceinline__ float bfhi(uint32_t u) { return __uint_as_float(u & 0xffff0000u); }

__constant__ float c_NLf[16] = {16.f,22.f,30.f,42.f,58.f,80.f,111.f,153.f,
                                212.f,293.f,406.f,561.f,775.f,1071.f,1481.f,2046.f};

// K0: f32 tables -> packed bf16 dwords (32 MB; 2 MB per level).
__global__ __launch_bounds__(256)
void cvt_tables(const float2* __restrict__ src, uint32_t* __restrict__ dst, int npairs)
{
    const int i = blockIdx.x * 256 + threadIdx.x;
    if (i >= npairs) return;
    const float2 v = src[i];
    dst[i] = (uint32_t)(uint16_t)f2bf(v.x) | ((uint32_t)(uint16_t)f2bf(v.y) << 16);
}

// ---------------------------------------------------------------------------
// K1: encode, one thread = one point x one LEVEL-PAIR (levels 2g, 2g+1).
// - 16 independent gathers in flight per lane (R5 had 8) -> 2x MLP.
// - blockIdx&7 = pair index: with round-robin block->XCD dispatch, XCD k
//   serves only pair k -> 4 MB packed tables ~= one XCD's L2 (R5-style
//   affinity preserved; R6 showed losing it costs 20x FETCH).
// - Output: uint2 plane per pair, feats_pr[g*n+p] = {lvl 2g, lvl 2g+1};
//   8-B/lane coalesced writes, and the MLP reads pairs 2q,2q+1 coalesced.
// ---------------------------------------------------------------------------
template<bool PACKED>
__global__ __launch_bounds__(256)
void ngp_encode(const float* __restrict__ xg, const void* __restrict__ tables,
                uint2* __restrict__ feats_pr, int n)
{
    const int b = blockIdx.x;
    const int g = b & 7;                       // level pair
    const int p = (b >> 3) * 256 + threadIdx.x;
    if (p >= n) return;

    const float px = xg[3*p+0], py = xg[3*p+1], pz = xg[3*p+2];
    float sx = px / 3.0f, sy = py / 3.0f, sz = pz / 3.0f;
    if (!((fabsf(sx) < 0.5f) && (fabsf(sy) < 0.5f) && (fabsf(sz) < 0.5f))) {
        feats_pr[(size_t)g * n + p] = make_uint2(0u, 0u);
        return;
    }
    sx = fminf(fmaxf(sx + 0.5f, 0.0f), 1.0f);
    sy = fminf(fmaxf(sy + 0.5f, 0.0f), 1.0f);
    sz = fminf(fmaxf(sz + 0.5f, 0.0f), 1.0f);

    uint32_t res[2];
    #pragma unroll
    for (int s = 0; s < 2; ++s) {
        const int l = 2*g + s;
        const float nf = c_NLf[l];
        const float xn0 = sx * nf, xn1 = sy * nf, xn2 = sz * nf;
        const float fl0 = floorf(xn0), fl1 = floorf(xn1), fl2 = floorf(xn2);
        const float w0 = xn0 - fl0, w1 = xn1 - fl1, w2 = xn2 - fl2;
        const uint32_t f0 = (uint32_t)fl0, f1 = (uint32_t)fl1, f2 = (uint32_t)fl2;
        const uint32_t c0 = (uint32_t)ceilf(xn0);
        const uint32_t c1 = (uint32_t)ceilf(xn1);
        const uint32_t c2 = (uint32_t)ceilf(xn2);
        const uint32_t hyf = f1 * 2654435761u, hyc = c1 * 2654435761u;
        const uint32_t hzf = f2 * 805459861u,  hzc = c2 * 805459861u;
        const uint32_t h0 = (f0 ^ hyf ^ hzf) & TMASK, h1 = (c0 ^ hyf ^ hzf) & TMASK;
        const uint32_t h2 = (f0 ^ hyc ^ hzf) & TMASK, h3 = (c0 ^ hyc ^ hzf) & TMASK;
        const uint32_t h4 = (f0 ^ hyf ^ hzc) & TMASK, h5 = (c0 ^ hyf ^ hzc) & TMASK;
        const uint32_t h6 = (f0 ^ hyc ^ hzc) & TMASK, h7 = (c0 ^ hyc ^ hzc) & TMASK;

        float v0x,v0y,v1x,v1y,v2x,v2y,v3x,v3y,v4x,v4y,v5x,v5y,v6x,v6y,v7x,v7y;
        if (PACKED) {
            const uint32_t* tb = (const uint32_t*)tables + (size_t)l * TS;
            const uint32_t e0 = tb[h0], e1 = tb[h1], e2 = tb[h2], e3 = tb[h3];
            const uint32_t e4 = tb[h4], e5 = tb[h5], e6 = tb[h6], e7 = tb[h7];
            v0x = bflo(e0); v0y = bfhi(e0); v1x = bflo(e1); v1y = bfhi(e1);
            v2x = bflo(e2); v2y = bfhi(e2); v3x = bflo(e3); v3y = bfhi(e3);
            v4x = bflo(e4); v4y = bfhi(e4); v5x = bflo(e5); v5y = bfhi(e5);
            v6x = bflo(e6); v6y = bfhi(e6); v7x = bflo(e7); v7y = bfhi(e7);
        } else {
            const float2* tb = (const float2*)tables + (size_t)l * TS;
            const float2 e0 = tb[h0], e1 = tb[h1], e2 = tb[h2], e3 = tb[h3];
            const float2 e4 = tb[h4], e5 = tb[h5], e6 = tb[h6], e7 = tb[h7];
            v0x = e0.x; v0y = e0.y; v1x = e1.x; v1y = e1.y;
            v2x = e2.x; v2y = e2.y; v3x = e3.x; v3y = e3.y;
            v4x = e4.x; v4y = e4.y; v5x = e5.x; v5y = e5.y;
            v6x = e6.x; v6y = e6.y; v7x = e7.x; v7y = e7.y;
        }

        const float u0 = 1.0f - w0, u1 = 1.0f - w1, u2 = 1.0f - w2;
        float a0, a1;
        a0 = u0*u1*u2 * v0x;              a1 = u0*u1*u2 * v0y;
        a0 = fmaf(w0*u1*u2, v1x, a0);     a1 = fmaf(w0*u1*u2, v1y, a1);
        a0 = fmaf(u0*w1*u2, v2x, a0);     a1 = fmaf(u0*w1*u2, v2y, a1);
        a0 = fmaf(w0*w1*u2, v3x, a0);     a1 = fmaf(w0*w1*u2, v3y, a1);
        a0 = fmaf(u0*u1*w2, v4x, a0);     a1 = fmaf(u0*u1*w2, v4y, a1);
        a0 = fmaf(w0*u1*w2, v5x, a0);     a1 = fmaf(w0*u1*w2, v5y, a1);
        a0 = fmaf(u0*w1*w2, v6x, a0);     a1 = fmaf(u0*w1*w2, v6y, a1);
        a0 = fmaf(w0*w1*w2, v7x, a0);     a1 = fmaf(w0*w1*w2, v7y, a1);

        res[s] = (uint32_t)(uint16_t)f2bf(a0) | ((uint32_t)(uint16_t)f2bf(a1) << 16);
    }
    feats_pr[(size_t)g * n + p] = make_uint2(res[0], res[1]);
}

// ---------------------------------------------------------------------------
// K2: MFMA MLP, persistent blocks, wave = 16 points. NO inter-layer barriers:
// act buffers are per-wave (R6 validated correctness), so waves drift freely
// and a feats-gather-stalled wave co-schedules with MFMA-phase waves (m114).
// Only barrier: after the once-per-block weight prepack.
// ---------------------------------------------------------------------------
#define ACT_STRIDE 72

__global__ __launch_bounds__(256)
void ngp_mlp_mfma(const float* __restrict__ xg, const float* __restrict__ dg,
                  const uint2* __restrict__ feats_pr,
                  const float* __restrict__ dW1, const float* __restrict__ db1,
                  const float* __restrict__ dW2, const float* __restrict__ db2,
                  const float* __restrict__ cW1, const float* __restrict__ cb1,
                  const float* __restrict__ cW2, const float* __restrict__ cb2,
                  const float* __restrict__ cW3, const float* __restrict__ cb3,
                  float* __restrict__ out, int n)
{
    __shared__ __align__(16) short w1[2048];   // [jb4][lane64][e8]       L1: 32->64
    __shared__ __align__(16) short w2[1024];   // [kb2][lane64][e8]       L2: 64->16
    __shared__ __align__(16) short w3[4096];   // [jb4][kb2][lane64][e8]  L3: 64(pad43)->64
    __shared__ __align__(16) short w4[4096];   // [jb4][kb2][lane64][e8]  L4: 64->64
    __shared__ __align__(16) short w5[1024];   // [kb2][lane64][e8]       L5: 64->16(3 used)
    __shared__ float b1[64], b2[16], b3[64], b4[64], b5[16];
    __shared__ __align__(16) short act[4][2][16*ACT_STRIDE];   // [wave][buf][...]

    const int tid = threadIdx.x;

    for (int idx = tid; idx < 2048; idx += 256) {
        const int jb = idx >> 9, lane = (idx >> 3) & 63, e = idx & 7;
        const int j = jb*16 + (lane & 15), k = ((lane >> 4) << 3) + e;
        w1[idx] = f2bf(dW1[k*64 + j]);
    }
    for (int idx = tid; idx < 1024; idx += 256) {
        const int kb = idx >> 9, lane = (idx >> 3) & 63, e = idx & 7;
        const int j = lane & 15, k = kb*32 + ((lane >> 4) << 3) + e;
        w2[idx] = f2bf(dW2[k*16 + j]);
    }
    for (int idx = tid; idx < 4096; idx += 256) {
        const int jb = idx >> 10, kb = (idx >> 9) & 1, lane = (idx >> 3) & 63, e = idx & 7;
        const int j = jb*16 + (lane & 15), k = kb*32 + ((lane >> 4) << 3) + e;
        w3[idx] = (k < 43) ? f2bf(cW1[k*64 + j]) : (short)0;
        w4[idx] = f2bf(cW2[k*64 + j]);
    }
    for (int idx = tid; idx < 1024; idx += 256) {
        const int kb = idx >> 9, lane = (idx >> 3) & 63, e = idx & 7;
        const int j = lane & 15, k = kb*32 + ((lane >> 4) << 3) + e;
        w5[idx] = (j < 3) ? f2bf(cW3[k*3 + j]) : (short)0;
    }
    if (tid < 64) { b1[tid] = db1[tid]; b3[tid] = cb1[tid]; b4[tid] = cb2[tid]; }
    if (tid < 16) { b2[tid] = db2[tid]; b5[tid] = (tid < 3) ? cb3[tid] : 0.0f; }
    __syncthreads();   // only barrier; weights/biases read-only afterwards

    const int wv = tid >> 6, lane = tid & 63;
    const int p16 = lane & 15, quad = lane >> 4;
    short* buf0 = &act[wv][0][0];
    short* buf1 = &act[wv][1][0];

    const int ntiles = (n + 63) >> 6;
    for (int t = blockIdx.x; t < ntiles; t += gridDim.x) {
        const int pp_raw = t*64 + wv*16 + p16;
        const int pp = (pp_raw < n) ? pp_raw : (n - 1);
        const bool valid = (pp_raw < n);

        const float mx = xg[3*pp+0] / 3.0f, my = xg[3*pp+1] / 3.0f, mz = xg[3*pp+2] / 3.0f;
        const bool inside = (fabsf(mx) < 0.5f) && (fabsf(my) < 0.5f) && (fabsf(mz) < 0.5f);

        // B-frag: k=quad*8+e -> level 4*quad+(e>>1) -> pairs 2*quad, 2*quad+1
        union { uint2 u[2]; bf16x8 v; } bu;
        bu.u[0] = feats_pr[(size_t)(2*quad+0)*n + pp];
        bu.u[1] = feats_pr[(size_t)(2*quad+1)*n + pp];
        const bf16x8 bA = bu.v;

        // ---- L1: feats[32] -> hid[64], relu ----
        #pragma unroll
        for (int jb = 0; jb < 4; ++jb) {
            const int j0 = jb*16 + quad*4;
            f32x4 acc = { b1[j0], b1[j0+1], b1[j0+2], b1[j0+3] };
            const bf16x8 aF = *reinterpret_cast<const bf16x8*>(&w1[(jb*64 + lane)*8]);
            acc = __builtin_amdgcn_mfma_f32_16x16x32_bf16(aF, bA, acc, 0, 0, 0);
            short4v s;
            s[0] = f2bf(fmaxf(acc[0], 0.f)); s[1] = f2bf(fmaxf(acc[1], 0.f));
            s[2] = f2bf(fmaxf(acc[2], 0.f)); s[3] = f2bf(fmaxf(acc[3], 0.f));
            *reinterpret_cast<short4v*>(&buf0[p16*ACT_STRIDE + j0]) = s;
        }

        // ---- L2: hid[64] -> h16[16] ----
        f32x4 acc2 = { b2[quad*4], b2[quad*4+1], b2[quad*4+2], b2[quad*4+3] };
        #pragma unroll
        for (int kb = 0; kb < 2; ++kb) {
            const bf16x8 bF = *reinterpret_cast<const bf16x8*>(&buf0[p16*ACT_STRIDE + kb*32 + quad*8]);
            const bf16x8 aF = *reinterpret_cast<const bf16x8*>(&w2[(kb*64 + lane)*8]);
            acc2 = __builtin_amdgcn_mfma_f32_16x16x32_bf16(aF, bF, acc2, 0, 0, 0);
        }
        if (quad == 0 && valid)
            out[(size_t)3*n + pp] = inside ? __expf(acc2[0]) : 0.0f;
        {
            short4v s;
            s[0] = f2bf(acc2[0]); s[1] = f2bf(acc2[1]);
            s[2] = f2bf(acc2[2]); s[3] = f2bf(acc2[3]);
            *reinterpret_cast<short4v*>(&buf1[p16*ACT_STRIDE + quad*4]) = s;
        }
        {   // pos-enc -> buf1[p][16..42], zeros [43..63]
            const float d0 = dg[3*pp+0], d1 = dg[3*pp+1], d2 = dg[3*pp+2];
            for (int idx = 16 + quad; idx < 64; idx += 4) {
                float val = 0.0f;
                if (idx < 19) {
                    val = (idx == 16) ? d0 : ((idx == 17) ? d1 : d2);
                } else if (idx < 43) {
                    const int g = idx - 19, f = g / 6, rem = g - 6*f;
                    const int c = (rem < 3) ? rem : rem - 3;
                    const float arg = ((c == 0) ? d0 : ((c == 1) ? d1 : d2)) * (float)(1 << f);
                    val = (rem < 3) ? __sinf(arg) : __cosf(arg);
                }
                buf1[p16*ACT_STRIDE + idx] = f2bf(val);
            }
        }

        // ---- L3 ----
        #pragma unroll
        for (int jb = 0; jb < 4; ++jb) {
            const int j0 = jb*16 + quad*4;
            f32x4 acc = { b3[j0], b3[j0+1], b3[j0+2], b3[j0+3] };
            #pragma unroll
            for (int kb = 0; kb < 2; ++kb) {
                const bf16x8 bF = *reinterpret_cast<const bf16x8*>(&buf1[p16*ACT_STRIDE + kb*32 + quad*8]);
                const bf16x8 aF = *reinterpret_cast<const bf16x8*>(&w3[((jb*2 + kb)*64 + lane)*8]);
                acc = __builtin_amdgcn_mfma_f32_16x16x32_bf16(aF, bF, acc, 0, 0, 0);
            }
            short4v s;
            s[0] = f2bf(fmaxf(acc[0], 0.f)); s[1] = f2bf(fmaxf(acc[1], 0.f));
            s[2] = f2bf(fmaxf(acc[2], 0.f)); s[3] = f2bf(fmaxf(acc[3], 0.f));
            *reinterpret_cast<short4v*>(&buf0[p16*ACT_STRIDE + j0]) = s;
        }

        // ---- L4 ----
        #pragma unroll
        for (int jb = 0; jb < 4; ++jb) {
            const int j0 = jb*16 + quad*4;
            f32x4 acc = { b4[j0], b4[j0+1], b4[j0+2], b4[j0+3] };
            #pragma unroll
            for (int kb = 0; kb < 2; ++kb) {
                const bf16x8 bF = *reinterpret_cast<const bf16x8*>(&buf0[p16*ACT_STRIDE + kb*32 + quad*8]);
                const bf16x8 aF = *reinterpret_cast<const bf16x8*>(&w4[((jb*2 + kb)*64 + lane)*8]);
                acc = __builtin_amdgcn_mfma_f32_16x16x32_bf16(aF, bF, acc, 0, 0, 0);
            }
            short4v s;
            s[0] = f2bf(fmaxf(acc[0], 0.f)); s[1] = f2bf(fmaxf(acc[1], 0.f));
            s[2] = f2bf(fmaxf(acc[2], 0.f)); s[3] = f2bf(fmaxf(acc[3], 0.f));
            *reinterpret_cast<short4v*>(&buf1[p16*ACT_STRIDE + j0]) = s;
        }

        // ---- L5 + sigmoid + store ----
        f32x4 acc5 = { b5[quad*4], b5[quad*4+1], b5[quad*4+2], b5[quad*4+3] };
        #pragma unroll
        for (int kb = 0; kb < 2; ++kb) {
            const bf16x8 bF = *reinterpret_cast<const bf16x8*>(&buf1[p16*ACT_STRIDE + kb*32 + quad*8]);
            const bf16x8 aF = *reinterpret_cast<const bf16x8*>(&w5[(kb*64 + lane)*8]);
            acc5 = __builtin_amdgcn_mfma_f32_16x16x32_bf16(aF, bF, acc5, 0, 0, 0);
        }
        if (quad == 0 && valid) {
            #pragma unroll
            for (int r = 0; r < 3; ++r) {
                const float s = 1.0f / (1.0f + __expf(-acc5[r]));
                out[3*pp + r] = inside ? s : 0.0f;
            }
        }
        // no barrier: act buffers per-wave; intra-wave LDS RAW handled by lgkmcnt
    }
}

extern "C" void kernel_launch(void* const* d_in, const int* in_sizes, int n_in,
                              void* d_out, int out_size, void* d_ws, size_t ws_size,
                              hipStream_t stream)
{
    const float* x   = (const float*)d_in[0];
    const float* d   = (const float*)d_in[1];
    const float* tb  = (const float*)d_in[2];
    const float* dW1 = (const float*)d_in[3];
    const float* db1 = (const float*)d_in[4];
    const float* dW2 = (const float*)d_in[5];
    const float* db2 = (const float*)d_in[6];
    const float* cW1 = (const float*)d_in[7];
    const float* cb1 = (const float*)d_in[8];
    const float* cW2 = (const float*)d_in[9];
    const float* cb2 = (const float*)d_in[10];
    const float* cW3 = (const float*)d_in[11];
    const float* cb3 = (const float*)d_in[12];
    float* out = (float*)d_out;

    const int n = in_sizes[0] / 3;                          // N_PTS = 1M
    const size_t feats_bytes = (size_t)n * 8 * sizeof(uint2);  // 8 pair-planes, 64 MB
    const size_t tb16_bytes  = (size_t)16 * TS * 4;            // 32 MB
    uint2*    feats_pr = (uint2*)d_ws;
    uint32_t* tb16     = (uint32_t*)((char*)d_ws + feats_bytes);
    const bool packed_ok = (ws_size >= feats_bytes + tb16_bytes);

    if (packed_ok) {
        const int npairs = 16 * (int)TS;
        dim3 block(256), grid((npairs + 255) / 256);
        hipLaunchKernelGGL(cvt_tables, grid, block, 0, stream,
                           (const float2*)tb, tb16, npairs);
    }
    {
        const int tiles = (n + 255) / 256;
        dim3 block(256), grid(tiles * 8);       // pair = blockIdx.x & 7
        if (packed_ok)
            hipLaunchKernelGGL((ngp_encode<true>),  grid, block, 0, stream, x, (const void*)tb16, feats_pr, n);
        else
            hipLaunchKernelGGL((ngp_encode<false>), grid, block, 0, stream, x, (const void*)tb,   feats_pr, n);
    }
    {
        const int ntiles = (n + 63) >> 6;
        const int nblk = (ntiles < 1280) ? ntiles : 1280;   // ~5 blocks/CU
        dim3 block(256), grid(nblk);
        hipLaunchKernelGGL(ngp_mlp_mfma, grid, block, 0, stream,
                           x, d, feats_pr, dW1, db1, dW2, db2,
                           cW1, cb1, cW2, cb2, cW3, cb3, out, n);
    }
}